// Round 5
// baseline (295.025 us; speedup 1.0000x reference)
//
#include <hip/hip_runtime.h>
#include <math.h>

#define B_  8
#define S_  8192
#define D_  64
#define H_  8
#define NB_ 128
#define NC_ 1024
#define REP_CAP 65536
#define T2_ 2e-3f   // repair margin >= 4x (split-f16 err ~1e-4 + key perturb ~2.5e-4)

typedef _Float16 f16x8 __attribute__((ext_vector_type(8)));
typedef _Float16 f16x2 __attribute__((ext_vector_type(2)));
typedef float    f32x4 __attribute__((ext_vector_type(4)));
typedef unsigned int uint_;

#define MFMA16(A, Bv, C) __builtin_amdgcn_mfma_f32_16x16x32_f16(A, Bv, C, 0, 0, 0)

// ---------------------------------------------------------------------------
// Kernel 0a: rot prep — transpose+split rot into [h][i][f] f16 hi/lo; zero cnt.
// ---------------------------------------------------------------------------
__global__ __launch_bounds__(256) void prep_rot_kernel(
    const float* __restrict__ rot, _Float16* __restrict__ rotHi,
    _Float16* __restrict__ rotLo, int* __restrict__ cnt)
{
  __shared__ float rs[64 * 64];               // [f][i]
  const int tid = threadIdx.x, h = blockIdx.x;
  if (h == 0 && tid == 0) *cnt = 0;
#pragma unroll
  for (int it = 0; it < 16; ++it) {
    const int f = it * 4 + (tid >> 6), i = tid & 63;
    rs[f * 64 + i] = rot[f * 512 + h * 64 + i];
  }
  __syncthreads();
  const int i = tid & 63, grp = tid >> 6;
  _Float16 hi[16], lo[16];
#pragma unroll
  for (int ff = 0; ff < 16; ++ff) {
    const float x = rs[(grp * 16 + ff) * 64 + i];
    hi[ff] = (_Float16)x;
    lo[ff] = (_Float16)(x - (float)hi[ff]);
  }
  f16x8* dH = (f16x8*)(rotHi + h * 4096 + i * 64 + grp * 16);
  f16x8* dL = (f16x8*)(rotLo + h * 4096 + i * 64 + grp * 16);
  dH[0] = ((f16x8*)hi)[0]; dH[1] = ((f16x8*)hi)[1];
  dL[0] = ((f16x8*)lo)[0]; dL[1] = ((f16x8*)lo)[1];
}

// ---------------------------------------------------------------------------
// Kernel 0b: token prep — q16 (f16 hi, shared by hash+attn-Q), qlo (hash lo),
// kn16 (pre-normalized keys, fp32 norm), v16.
// ---------------------------------------------------------------------------
__global__ __launch_bounds__(256) void prep_tok_kernel(
    const float* __restrict__ qk, const float* __restrict__ v,
    _Float16* __restrict__ q16, _Float16* __restrict__ qlo,
    _Float16* __restrict__ kn16, _Float16* __restrict__ v16)
{
  const int gt = blockIdx.x * 64 + (threadIdx.x >> 2);   // token over B*S
  const int qu = threadIdx.x & 3;
  const size_t off = (size_t)gt * 64 + qu * 16;
  float x[16];
#pragma unroll
  for (int k = 0; k < 4; ++k) ((float4*)x)[k] = ((const float4*)(qk + off))[k];
  float ss = 0.f;
#pragma unroll
  for (int k = 0; k < 16; ++k) ss = fmaf(x[k], x[k], ss);
  ss += __shfl_xor(ss, 1); ss += __shfl_xor(ss, 2);
  const float inv = 0.125f / (sqrtf(ss) + 1e-6f);        // D^-0.5 folded in
  f16x8 qh[2], ql[2], kn[2];
#pragma unroll
  for (int j = 0; j < 16; ++j) {
    const _Float16 hi = (_Float16)x[j];
    qh[j >> 3][j & 7] = hi;
    ql[j >> 3][j & 7] = (_Float16)(x[j] - (float)hi);
    kn[j >> 3][j & 7] = (_Float16)(x[j] * inv);
  }
  ((f16x8*)(q16  + off))[0] = qh[0]; ((f16x8*)(q16  + off))[1] = qh[1];
  ((f16x8*)(qlo  + off))[0] = ql[0]; ((f16x8*)(qlo  + off))[1] = ql[1];
  ((f16x8*)(kn16 + off))[0] = kn[0]; ((f16x8*)(kn16 + off))[1] = kn[1];
  float y[16];
#pragma unroll
  for (int k = 0; k < 4; ++k) ((float4*)y)[k] = ((const float4*)(v + off))[k];
  f16x8 vv[2];
#pragma unroll
  for (int j = 0; j < 16; ++j) vv[j >> 3][j & 7] = (_Float16)y[j];
  ((f16x8*)(v16 + off))[0] = vv[0]; ((f16x8*)(v16 + off))[1] = vv[1];
}

// ---------------------------------------------------------------------------
// Kernel 1: hash via split-f16 MFMA, zero LDS / zero barriers.
// D[i][token] = rot^T q. A-frags direct from rotHi/Lo (L1/L2-hot), B-frags
// direct from q16/qlo (fragment-shaped rows). Reduction: index packed into
// low-6 mantissa bits (v_and_or), top-2 via v_med3. Any decision within
// 64 ulps of a flip falls inside the T2 repair margin -> fp64-exact buckets.
// ---------------------------------------------------------------------------
__global__ __launch_bounds__(256) void hash_kernel(
    const _Float16* __restrict__ q16, const _Float16* __restrict__ qlo,
    const _Float16* __restrict__ rotHi, const _Float16* __restrict__ rotLo,
    int* __restrict__ bucket, int* __restrict__ cnt, int2* __restrict__ list)
{
  const int tid  = threadIdx.x;
  const int tile = blockIdx.x & 63;           // 64 tiles x 128 tokens
  const int bh   = blockIdx.x >> 6;
  const int h    = bh & 7, b = bh >> 3;
  const int lane = tid & 63, w = tid >> 6;
  const int m16  = lane & 15, qd = lane >> 4;

  f16x8 AH[4][2], AL[4][2];
  {
    const _Float16* rbH = rotHi + h * 4096;
    const _Float16* rbL = rotLo + h * 4096;
#pragma unroll
    for (int mt = 0; mt < 4; ++mt) {
      const int row = (16 * mt + m16) * 64 + 8 * qd;
      AH[mt][0] = *(const f16x8*)(rbH + row);
      AH[mt][1] = *(const f16x8*)(rbH + row + 32);
      AL[mt][0] = *(const f16x8*)(rbL + row);
      AL[mt][1] = *(const f16x8*)(rbL + row + 32);
    }
  }

  const uint_ qd16 = (uint_)(qd << 4);
#pragma unroll 1
  for (int p = 0; p < 2; ++p) {               // 2 token-tiles per wave
    const int t = tile * 128 + w * 32 + p * 16 + m16;
    const size_t qoff = ((size_t)b * S_ + t) * 64 + 8 * qd;
    const f16x8 bhi0 = *(const f16x8*)(q16 + qoff);
    const f16x8 bhi1 = *(const f16x8*)(q16 + qoff + 32);
    const f16x8 blo0 = *(const f16x8*)(qlo + qoff);
    const f16x8 blo1 = *(const f16x8*)(qlo + qoff + 32);

    f32x4 acc[4];
#pragma unroll
    for (int mt = 0; mt < 4; ++mt) acc[mt] = (f32x4){0.f, 0.f, 0.f, 0.f};
#pragma unroll
    for (int mt = 0; mt < 4; ++mt) {
      acc[mt] = MFMA16(AH[mt][0], bhi0, acc[mt]);
      acc[mt] = MFMA16(AH[mt][1], bhi1, acc[mt]);
      acc[mt] = MFMA16(AH[mt][0], blo0, acc[mt]);
      acc[mt] = MFMA16(AH[mt][1], blo1, acc[mt]);
      acc[mt] = MFMA16(AL[mt][0], bhi0, acc[mt]);
      acc[mt] = MFMA16(AL[mt][1], bhi1, acc[mt]);
    }

    float v1M = -1e30f, v2M = -1e30f, v1m = 1e30f, v2m = 1e30f;
#pragma unroll
    for (int mt = 0; mt < 4; ++mt)
#pragma unroll
      for (int rg = 0; rg < 4; ++rg) {
        uint_ u = __float_as_uint(acc[mt][rg]);
        u = (u & 0xFFFFFFC0u) | qd16 | (uint_)((mt << 2) | rg);
        const float xk = __uint_as_float(u);
        v2M = __builtin_amdgcn_fmed3f(v1M, v2M, xk);
        v1M = fmaxf(v1M, xk);
        v2m = __builtin_amdgcn_fmed3f(v1m, v2m, xk);
        v1m = fminf(v1m, xk);
      }
#pragma unroll
    for (int off = 16; off <= 32; off <<= 1) {  // merge the 4 qd-lanes
      const float o1M = __shfl_xor(v1M, off), o2M = __shfl_xor(v2M, off);
      v2M = __builtin_amdgcn_fmed3f(v1M, o1M, fmaxf(v2M, o2M));
      v1M = fmaxf(v1M, o1M);
      const float o1m = __shfl_xor(v1m, off), o2m = __shfl_xor(v2m, off);
      v2m = __builtin_amdgcn_fmed3f(v1m, o1m, fminf(v2m, o2m));
      v1m = fminf(v1m, o1m);
    }
    if (qd == 0) {
      const uint_ cM = __float_as_uint(v1M) & 63u;
      const uint_ cm = __float_as_uint(v1m) & 63u;
      const int ixM = 16 * (int)((cM >> 2) & 3u) + 4 * (int)(cM >> 4) + (int)(cM & 3u);
      const int ixm = 16 * (int)((cm >> 2) & 3u) + 4 * (int)(cm >> 4) + (int)(cm & 3u);
      const int bkt = (v1M >= -v1m) ? ixM : 64 + ixm;
      bucket[(size_t)bh * S_ + t] = bkt;
      const bool flag = ((v1M - v2M) < T2_) | ((v2m - v1m) < T2_) |
                        (fabsf(v1M + v1m) < T2_);
      if (flag) {
        const int s = atomicAdd(cnt, 1);
        if (s < REP_CAP) list[s] = make_int2(bh, t);
      }
    }
  }
}

// ---------------------------------------------------------------------------
// Kernel 1b: exact fp64 repair for flagged tokens. One wave per token.
// ---------------------------------------------------------------------------
__global__ __launch_bounds__(256) void repair_kernel(
    const float* __restrict__ qk, const float* __restrict__ rot,
    const int* __restrict__ cnt, const int2* __restrict__ list,
    int* __restrict__ bucket)
{
  const int n = min(*cnt, REP_CAP);
  const int lane = threadIdx.x & 63;
  const int wid  = (blockIdx.x * 256 + threadIdx.x) >> 6;
  const int nw   = gridDim.x * 4;
  for (int idx = wid; idx < n; idx += nw) {
    const int bh = list[idx].x, t = list[idx].y;
    const int b = bh >> 3, hh = bh & 7;
    const float* qrow = qk + ((size_t)b * S_ + t) * D_;
    const float* rcol = rot + hh * 64 + lane;
    double acc = 0.0;
#pragma unroll 8
    for (int f = 0; f < 64; ++f)
      acc = fma((double)qrow[f], (double)rcol[(size_t)f * 512], acc);
    double vM = acc; int iM = lane;
    double vm = acc; int im = lane;
#pragma unroll
    for (int off = 32; off >= 1; off >>= 1) {
      const double voM = __shfl_xor(vM, off); const int ioM = __shfl_xor(iM, off);
      if (voM > vM || (voM == vM && ioM < iM)) { vM = voM; iM = ioM; }
      const double vom = __shfl_xor(vm, off); const int iom = __shfl_xor(im, off);
      if (vom < vm || (vom == vm && iom < im)) { vm = vom; im = iom; }
    }
    if (lane == 0) {
      const int bkt = (vM >= -vm) ? iM : 64 + im;
      bucket[(size_t)bh * S_ + t] = bkt;
    }
  }
}

// ---------------------------------------------------------------------------
// Kernel 2: stable counting sort per (b,h). Unchanged.
// ---------------------------------------------------------------------------
__global__ __launch_bounds__(1024) void sort_kernel(
    const int* __restrict__ bucket, int* __restrict__ st,
    int* __restrict__ undo)
{
  __shared__ int lb[S_];
  __shared__ int hist[8 * 128];
  __shared__ int off[128];
  const int tid = threadIdx.x;
  const int bh  = blockIdx.x;
  const size_t base = (size_t)bh * S_;

  for (int k = tid; k < S_; k += 1024) lb[k] = bucket[base + k];
  hist[tid] = 0;
  __syncthreads();
  {
    const int seg = tid >> 7;
    const int t0 = tid * 8;
#pragma unroll
    for (int k = 0; k < 8; ++k) atomicAdd(&hist[seg * 128 + lb[t0 + k]], 1);
  }
  __syncthreads();
  if (tid < 128) {
    int s = 0;
#pragma unroll
    for (int g = 0; g < 8; ++g) s += hist[g * 128 + tid];
    off[tid] = s;
  }
  __syncthreads();
  if (tid == 0) {
    int run = 0;
    for (int k = 0; k < 128; ++k) { const int c = off[k]; off[k] = run; run += c; }
  }
  __syncthreads();
  if (tid < 128) {
    int run = off[tid];
#pragma unroll
    for (int g = 0; g < 8; ++g) { const int c = hist[g * 128 + tid]; hist[g * 128 + tid] = run; run += c; }
  }
  __syncthreads();
  const int bkt = tid & 127;
  const int seg = tid >> 7;
  int pos = hist[seg * 128 + bkt];
  const int sbase = seg * 1024;
  const int b = bh >> 3, h = bh & 7;
  const size_t stb = (size_t)b * (H_ * S_) + (size_t)h * S_;
  for (int k = 0; k < 1024; ++k) {
    const int t = sbase + k;
    if (lb[t] == bkt) {
      st[stb + pos] = t;
      undo[base + t] = h * S_ + pos;
      ++pos;
    }
  }
}

// ---------------------------------------------------------------------------
// Kernel 3: bucketed attention, f16 MFMA, pre-converted f16 gathers, f16 so.
// ---------------------------------------------------------------------------
__global__ __launch_bounds__(256, 4) void attn_kernel(
    const _Float16* __restrict__ q16, const _Float16* __restrict__ kn16,
    const _Float16* __restrict__ v16, const int* __restrict__ st,
    _Float16* __restrict__ so, float* __restrict__ slogits)
{
  __shared__ _Float16 sQ[64 * 72];
  __shared__ _Float16 sK[64 * 72];
  __shared__ _Float16 sP[64 * 136];
  __shared__ int sIds[128];

  const int tid = threadIdx.x;
  const int c   = blockIdx.x & (NC_ - 1);
  const int b   = blockIdx.x >> 10;
  const int cm1 = (c + NC_ - 1) & (NC_ - 1);
  const size_t bst = (size_t)b * (H_ * S_);
  const size_t row0 = bst + (size_t)c * 64;
  const size_t row1 = bst + (size_t)cm1 * 64;

  const int lane = tid & 63;
  const int w    = tid >> 6;
  const int m16  = lane & 15;
  const int qd   = lane >> 4;

  if (tid < 128) sIds[tid] = (tid < 64) ? st[row0 + tid] : st[row1 + tid - 64];

  const int r = tid >> 2, qu = tid & 3;
  {                                           // stage Q + K rows 0..63 (copies)
    const int tok = st[row0 + r];
    const size_t go = ((size_t)b * S_ + tok) * 64 + qu * 16;
    const f16x8* sq = (const f16x8*)(q16 + go);
    *(f16x8*)(sQ + r * 72 + qu * 16)     = sq[0];
    *(f16x8*)(sQ + r * 72 + qu * 16 + 8) = sq[1];
    const f16x8* sk = (const f16x8*)(kn16 + go);
    *(f16x8*)(sK + r * 72 + qu * 16)     = sk[0];
    *(f16x8*)(sK + r * 72 + qu * 16 + 8) = sk[1];
  }
  __syncthreads();                            // b0

  f32x4 acc[8];
#pragma unroll
  for (int jt = 0; jt < 8; ++jt) acc[jt] = (f32x4){0.f, 0.f, 0.f, 0.f};

  const _Float16* qrow = sQ + (16 * w + m16) * 72;
  const f16x8 a0 = *(const f16x8*)(qrow + 8 * qd);
  const f16x8 a1 = *(const f16x8*)(qrow + 32 + 8 * qd);

#pragma unroll
  for (int jt = 0; jt < 4; ++jt) {
    const _Float16* krow = sK + (16 * jt + m16) * 72;
    const f16x8 b0 = *(const f16x8*)(krow + 8 * qd);
    const f16x8 b1 = *(const f16x8*)(krow + 32 + 8 * qd);
    acc[jt] = MFMA16(a0, b0, acc[jt]);
    acc[jt] = MFMA16(a1, b1, acc[jt]);
  }
  __syncthreads();                            // b1

  {                                           // restage K rows 64..127
    const int tok = st[row1 + r];
    const f16x8* sk = (const f16x8*)(kn16 + ((size_t)b * S_ + tok) * 64 + qu * 16);
    *(f16x8*)(sK + r * 72 + qu * 16)     = sk[0];
    *(f16x8*)(sK + r * 72 + qu * 16 + 8) = sk[1];
  }
  __syncthreads();                            // b2

#pragma unroll
  for (int jt = 4; jt < 8; ++jt) {
    const _Float16* krow = sK + (16 * (jt - 4) + m16) * 72;
    const f16x8 b0 = *(const f16x8*)(krow + 8 * qd);
    const f16x8 b1 = *(const f16x8*)(krow + 32 + 8 * qd);
    acc[jt] = MFMA16(a0, b0, acc[jt]);
    acc[jt] = MFMA16(a1, b1, acc[jt]);
  }

  // issue V gather loads early (consumed after barrier b3)
  const int jp = tid >> 2;
  const int tok0 = sIds[2 * jp], tok1 = sIds[2 * jp + 1];
  f16x8 va[2], vb[2];
  {
    const f16x8* s0 = (const f16x8*)(v16 + ((size_t)b * S_ + tok0) * 64 + qu * 16);
    const f16x8* s1 = (const f16x8*)(v16 + ((size_t)b * S_ + tok1) * 64 + qu * 16);
    va[0] = s0[0]; va[1] = s0[1];
    vb[0] = s1[0]; vb[1] = s1[1];
  }

  // self-mask + softmax (registers + 16-lane shuffles)
  int rid[4];
#pragma unroll
  for (int rg = 0; rg < 4; ++rg) rid[rg] = sIds[16 * w + 4 * qd + rg];
  float rmax[4] = {-1e30f, -1e30f, -1e30f, -1e30f};
#pragma unroll
  for (int jt = 0; jt < 8; ++jt) {
    const int cid = sIds[16 * jt + m16];
#pragma unroll
    for (int rg = 0; rg < 4; ++rg) {
      float x = acc[jt][rg];
      if (rid[rg] == cid) x = -5e4f;
      acc[jt][rg] = x;
      rmax[rg] = fmaxf(rmax[rg], x);
    }
  }
#pragma unroll
  for (int rg = 0; rg < 4; ++rg) {
    rmax[rg] = fmaxf(rmax[rg], __shfl_xor(rmax[rg], 1));
    rmax[rg] = fmaxf(rmax[rg], __shfl_xor(rmax[rg], 2));
    rmax[rg] = fmaxf(rmax[rg], __shfl_xor(rmax[rg], 4));
    rmax[rg] = fmaxf(rmax[rg], __shfl_xor(rmax[rg], 8));
  }
  float rsum[4] = {0.f, 0.f, 0.f, 0.f};
#pragma unroll
  for (int jt = 0; jt < 8; ++jt)
#pragma unroll
    for (int rg = 0; rg < 4; ++rg) {
      const float e = __expf(acc[jt][rg] - rmax[rg]);
      acc[jt][rg] = e;
      rsum[rg] += e;
    }
#pragma unroll
  for (int rg = 0; rg < 4; ++rg) {
    rsum[rg] += __shfl_xor(rsum[rg], 1);
    rsum[rg] += __shfl_xor(rsum[rg], 2);
    rsum[rg] += __shfl_xor(rsum[rg], 4);
    rsum[rg] += __shfl_xor(rsum[rg], 8);
  }
  float rinv[4];
#pragma unroll
  for (int rg = 0; rg < 4; ++rg) rinv[rg] = 1.f / rsum[rg];
  if (m16 == 0) {
#pragma unroll
    for (int rg = 0; rg < 4; ++rg)
      slogits[row0 + 16 * w + 4 * qd + rg] = rmax[rg] + __logf(rsum[rg]);
  }

  // p -> LDS [i][j] f16 (C/D -> A-layout transform)
#pragma unroll
  for (int jt = 0; jt < 8; ++jt)
#pragma unroll
    for (int rg = 0; rg < 4; ++rg)
      sP[(16 * w + 4 * qd + rg) * 136 + 16 * jt + m16] = (_Float16)acc[jt][rg];

  __syncthreads();                            // b3: sQ/sK reads done

  {                                           // stage vT: [d][j]
    const int j = 2 * jp;
    _Float16* dst = (j < 64) ? (sK + j) : (sQ + (j - 64));
#pragma unroll
    for (int jj = 0; jj < 16; ++jj) {
      const int d = qu * 16 + jj;
      f16x2 pk; pk[0] = va[jj >> 3][jj & 7]; pk[1] = vb[jj >> 3][jj & 7];
      *(f16x2*)(dst + d * 72) = pk;
    }
  }
  __syncthreads();                            // b4

  f32x4 oacc[4];
#pragma unroll
  for (int dt = 0; dt < 4; ++dt) oacc[dt] = (f32x4){0.f, 0.f, 0.f, 0.f};
  const _Float16* prow = sP + (16 * w + m16) * 136;
#pragma unroll
  for (int s = 0; s < 4; ++s) {
    const f16x8 ap = *(const f16x8*)(prow + 32 * s + 8 * qd);
    const _Float16* vbase = (s < 2) ? sK : sQ;
    const int col0 = 32 * (s & 1) + 8 * qd;
#pragma unroll
    for (int dt = 0; dt < 4; ++dt) {
      const f16x8 bv = *(const f16x8*)(vbase + (16 * dt + m16) * 72 + col0);
      oacc[dt] = MFMA16(ap, bv, oacc[dt]);
    }
  }

  const size_t ob = row0 * 64;
#pragma unroll
  for (int dt = 0; dt < 4; ++dt)
#pragma unroll
    for (int rg = 0; rg < 4; ++rg) {
      const int i = 16 * w + 4 * qd + rg;
      const int d = 16 * dt + m16;
      so[ob + (size_t)i * 64 + d] = (_Float16)(oacc[dt][rg] * rinv[rg]);
    }
}

// ---------------------------------------------------------------------------
// Kernel 4: un-sort + combine rounds (f16 so reads).
// ---------------------------------------------------------------------------
__global__ __launch_bounds__(256) void combine_kernel(
    const _Float16* __restrict__ so, const float* __restrict__ slogits,
    const int* __restrict__ undo, float* __restrict__ out)
{
  const int gt = blockIdx.x * 4 + (threadIdx.x >> 6);
  const int d  = threadIdx.x & 63;
  const int b  = gt >> 13;
  const int t  = gt & (S_ - 1);
  const size_t bst = (size_t)b * (H_ * S_);

  int p[8]; float l[8];
#pragma unroll
  for (int h = 0; h < 8; ++h) {
    p[h] = undo[((size_t)b * 8 + h) * S_ + t];
    l[h] = slogits[bst + p[h]];
  }
  float m = l[0];
#pragma unroll
  for (int h = 1; h < 8; ++h) m = fmaxf(m, l[h]);
  float wv[8], W = 0.f;
#pragma unroll
  for (int h = 0; h < 8; ++h) { wv[h] = expf(l[h] - m); W += wv[h]; }
  const float iW = 1.f / W;
  float acc = 0.f;
#pragma unroll
  for (int h = 0; h < 8; ++h)
    acc = fmaf(wv[h], (float)so[(bst + (size_t)p[h]) * 64 + d], acc);
  out[(size_t)gt * 64 + d] = acc * iW;
}

// ---------------------------------------------------------------------------
extern "C" void kernel_launch(void* const* d_in, const int* in_sizes, int n_in,
                              void* d_out, int out_size, void* d_ws, size_t ws_size,
                              hipStream_t stream)
{
  const float* qk  = (const float*)d_in[0];
  const float* v   = (const float*)d_in[1];
  const float* rot = (const float*)d_in[2];
  float* out = (float*)d_out;

  char* ws = (char*)d_ws;
  const size_t MB = 1ull << 20, KB = 1024;
  int*      bucket = (int*)      (ws + 0 * MB);   // 2 MB
  int*      st     = (int*)      (ws + 2 * MB);   // 2 MB
  int*      undo   = (int*)      (ws + 4 * MB);   // 2 MB
  float*    slog   = (float*)    (ws + 6 * MB);   // 2 MB
  _Float16* q16    = (_Float16*) (ws + 8 * MB);   // 8 MB
  _Float16* kn16   = (_Float16*) (ws + 16 * MB);  // 8 MB
  _Float16* v16    = (_Float16*) (ws + 24 * MB);  // 8 MB
  _Float16* qlo    = (_Float16*) (ws + 32 * MB);  // 8 MB
  _Float16* rotHi  = (_Float16*) (ws + 40 * MB);            // 64 KB
  _Float16* rotLo  = (_Float16*) (ws + 40 * MB + 64 * KB);  // 64 KB
  int*      cnt    = (int*)      (ws + 40 * MB + 128 * KB);
  int2*     list   = (int2*)     (ws + 40 * MB + 192 * KB); // 512 KB
  _Float16* so     = (_Float16*) (ws + 41 * MB);  // 64 MB -> ends at 105 MB
  if (ws_size < 106 * MB) return;

  hipLaunchKernelGGL(prep_rot_kernel, dim3(8),           dim3(256),  0, stream, rot, rotHi, rotLo, cnt);
  hipLaunchKernelGGL(prep_tok_kernel, dim3(1024),        dim3(256),  0, stream, qk, v, q16, qlo, kn16, v16);
  hipLaunchKernelGGL(hash_kernel,     dim3(64 * 64),     dim3(256),  0, stream, q16, qlo, rotHi, rotLo, bucket, cnt, list);
  hipLaunchKernelGGL(repair_kernel,   dim3(128),         dim3(256),  0, stream, qk, rot, cnt, list, bucket);
  hipLaunchKernelGGL(sort_kernel,     dim3(64),          dim3(1024), 0, stream, bucket, st, undo);
  hipLaunchKernelGGL(attn_kernel,     dim3(B_ * NC_),    dim3(256),  0, stream, q16, kn16, v16, st, so, slog);
  hipLaunchKernelGGL(combine_kernel,  dim3(B_ * S_ / 4), dim3(256),  0, stream, so, slog, undo, out);
}

// Round 6
// 235.586 us; speedup vs baseline: 1.2523x; 1.2523x over previous
//
#include <hip/hip_runtime.h>
#include <math.h>

#define B_  8
#define S_  8192
#define D_  64
#define H_  8
#define NB_ 128
#define NC_ 1024
#define REP_CAP 65536
#define T2_ 2e-3f   // repair margin >= 4x (split-f16 err ~1e-4 + key perturb ~2.5e-4)

typedef _Float16 f16x8 __attribute__((ext_vector_type(8)));
typedef _Float16 f16x2 __attribute__((ext_vector_type(2)));
typedef float    f32x4 __attribute__((ext_vector_type(4)));
typedef unsigned int uint_;

#define MFMA16(A, Bv, C) __builtin_amdgcn_mfma_f32_16x16x32_f16(A, Bv, C, 0, 0, 0)

// ---------------------------------------------------------------------------
// Kernel 0a: rot prep — transpose+split rot into [h][i][f] f16 hi/lo; zero cnt.
// ---------------------------------------------------------------------------
__global__ __launch_bounds__(256) void prep_rot_kernel(
    const float* __restrict__ rot, _Float16* __restrict__ rotHi,
    _Float16* __restrict__ rotLo, int* __restrict__ cnt)
{
  __shared__ float rs[64 * 64];               // [f][i]
  const int tid = threadIdx.x, h = blockIdx.x;
  if (h == 0 && tid == 0) *cnt = 0;
#pragma unroll
  for (int it = 0; it < 16; ++it) {
    const int f = it * 4 + (tid >> 6), i = tid & 63;
    rs[f * 64 + i] = rot[f * 512 + h * 64 + i];
  }
  __syncthreads();
  const int i = tid & 63, grp = tid >> 6;
  _Float16 hi[16], lo[16];
#pragma unroll
  for (int ff = 0; ff < 16; ++ff) {
    const float x = rs[(grp * 16 + ff) * 64 + i];
    hi[ff] = (_Float16)x;
    lo[ff] = (_Float16)(x - (float)hi[ff]);
  }
  f16x8* dH = (f16x8*)(rotHi + h * 4096 + i * 64 + grp * 16);
  f16x8* dL = (f16x8*)(rotLo + h * 4096 + i * 64 + grp * 16);
  dH[0] = ((f16x8*)hi)[0]; dH[1] = ((f16x8*)hi)[1];
  dL[0] = ((f16x8*)lo)[0]; dL[1] = ((f16x8*)lo)[1];
}

// ---------------------------------------------------------------------------
// Kernel 0b: token prep — q16 (f16 hi), qlo (hash lo), kn16 (pre-normalized
// keys), v16.
// ---------------------------------------------------------------------------
__global__ __launch_bounds__(256) void prep_tok_kernel(
    const float* __restrict__ qk, const float* __restrict__ v,
    _Float16* __restrict__ q16, _Float16* __restrict__ qlo,
    _Float16* __restrict__ kn16, _Float16* __restrict__ v16)
{
  const int gt = blockIdx.x * 64 + (threadIdx.x >> 2);
  const int qu = threadIdx.x & 3;
  const size_t off = (size_t)gt * 64 + qu * 16;
  float x[16];
#pragma unroll
  for (int k = 0; k < 4; ++k) ((float4*)x)[k] = ((const float4*)(qk + off))[k];
  float ss = 0.f;
#pragma unroll
  for (int k = 0; k < 16; ++k) ss = fmaf(x[k], x[k], ss);
  ss += __shfl_xor(ss, 1); ss += __shfl_xor(ss, 2);
  const float inv = 0.125f / (sqrtf(ss) + 1e-6f);
  f16x8 qh[2], ql[2], kn[2];
#pragma unroll
  for (int j = 0; j < 16; ++j) {
    const _Float16 hi = (_Float16)x[j];
    qh[j >> 3][j & 7] = hi;
    ql[j >> 3][j & 7] = (_Float16)(x[j] - (float)hi);
    kn[j >> 3][j & 7] = (_Float16)(x[j] * inv);
  }
  ((f16x8*)(q16  + off))[0] = qh[0]; ((f16x8*)(q16  + off))[1] = qh[1];
  ((f16x8*)(qlo  + off))[0] = ql[0]; ((f16x8*)(qlo  + off))[1] = ql[1];
  ((f16x8*)(kn16 + off))[0] = kn[0]; ((f16x8*)(kn16 + off))[1] = kn[1];
  float y[16];
#pragma unroll
  for (int k = 0; k < 4; ++k) ((float4*)y)[k] = ((const float4*)(v + off))[k];
  f16x8 vv[2];
#pragma unroll
  for (int j = 0; j < 16; ++j) vv[j >> 3][j & 7] = (_Float16)y[j];
  ((f16x8*)(v16 + off))[0] = vv[0]; ((f16x8*)(v16 + off))[1] = vv[1];
}

// ---------------------------------------------------------------------------
// Kernel 1: hash via split-f16 MFMA, zero LDS / zero barriers. Unchanged.
// ---------------------------------------------------------------------------
__global__ __launch_bounds__(256) void hash_kernel(
    const _Float16* __restrict__ q16, const _Float16* __restrict__ qlo,
    const _Float16* __restrict__ rotHi, const _Float16* __restrict__ rotLo,
    int* __restrict__ bucket, int* __restrict__ cnt, int2* __restrict__ list)
{
  const int tid  = threadIdx.x;
  const int tile = blockIdx.x & 63;
  const int bh   = blockIdx.x >> 6;
  const int h    = bh & 7, b = bh >> 3;
  const int lane = tid & 63, w = tid >> 6;
  const int m16  = lane & 15, qd = lane >> 4;

  f16x8 AH[4][2], AL[4][2];
  {
    const _Float16* rbH = rotHi + h * 4096;
    const _Float16* rbL = rotLo + h * 4096;
#pragma unroll
    for (int mt = 0; mt < 4; ++mt) {
      const int row = (16 * mt + m16) * 64 + 8 * qd;
      AH[mt][0] = *(const f16x8*)(rbH + row);
      AH[mt][1] = *(const f16x8*)(rbH + row + 32);
      AL[mt][0] = *(const f16x8*)(rbL + row);
      AL[mt][1] = *(const f16x8*)(rbL + row + 32);
    }
  }

  const uint_ qd16 = (uint_)(qd << 4);
#pragma unroll 1
  for (int p = 0; p < 2; ++p) {
    const int t = tile * 128 + w * 32 + p * 16 + m16;
    const size_t qoff = ((size_t)b * S_ + t) * 64 + 8 * qd;
    const f16x8 bhi0 = *(const f16x8*)(q16 + qoff);
    const f16x8 bhi1 = *(const f16x8*)(q16 + qoff + 32);
    const f16x8 blo0 = *(const f16x8*)(qlo + qoff);
    const f16x8 blo1 = *(const f16x8*)(qlo + qoff + 32);

    f32x4 acc[4];
#pragma unroll
    for (int mt = 0; mt < 4; ++mt) acc[mt] = (f32x4){0.f, 0.f, 0.f, 0.f};
#pragma unroll
    for (int mt = 0; mt < 4; ++mt) {
      acc[mt] = MFMA16(AH[mt][0], bhi0, acc[mt]);
      acc[mt] = MFMA16(AH[mt][1], bhi1, acc[mt]);
      acc[mt] = MFMA16(AH[mt][0], blo0, acc[mt]);
      acc[mt] = MFMA16(AH[mt][1], blo1, acc[mt]);
      acc[mt] = MFMA16(AL[mt][0], bhi0, acc[mt]);
      acc[mt] = MFMA16(AL[mt][1], bhi1, acc[mt]);
    }

    float v1M = -1e30f, v2M = -1e30f, v1m = 1e30f, v2m = 1e30f;
#pragma unroll
    for (int mt = 0; mt < 4; ++mt)
#pragma unroll
      for (int rg = 0; rg < 4; ++rg) {
        uint_ u = __float_as_uint(acc[mt][rg]);
        u = (u & 0xFFFFFFC0u) | qd16 | (uint_)((mt << 2) | rg);
        const float xk = __uint_as_float(u);
        v2M = __builtin_amdgcn_fmed3f(v1M, v2M, xk);
        v1M = fmaxf(v1M, xk);
        v2m = __builtin_amdgcn_fmed3f(v1m, v2m, xk);
        v1m = fminf(v1m, xk);
      }
#pragma unroll
    for (int off = 16; off <= 32; off <<= 1) {
      const float o1M = __shfl_xor(v1M, off), o2M = __shfl_xor(v2M, off);
      v2M = __builtin_amdgcn_fmed3f(v1M, o1M, fmaxf(v2M, o2M));
      v1M = fmaxf(v1M, o1M);
      const float o1m = __shfl_xor(v1m, off), o2m = __shfl_xor(v2m, off);
      v2m = __builtin_amdgcn_fmed3f(v1m, o1m, fminf(v2m, o2m));
      v1m = fminf(v1m, o1m);
    }
    if (qd == 0) {
      const uint_ cM = __float_as_uint(v1M) & 63u;
      const uint_ cm = __float_as_uint(v1m) & 63u;
      const int ixM = 16 * (int)((cM >> 2) & 3u) + 4 * (int)(cM >> 4) + (int)(cM & 3u);
      const int ixm = 16 * (int)((cm >> 2) & 3u) + 4 * (int)(cm >> 4) + (int)(cm & 3u);
      const int bkt = (v1M >= -v1m) ? ixM : 64 + ixm;
      bucket[(size_t)bh * S_ + t] = bkt;
      const bool flag = ((v1M - v2M) < T2_) | ((v2m - v1m) < T2_) |
                        (fabsf(v1M + v1m) < T2_);
      if (flag) {
        const int s = atomicAdd(cnt, 1);
        if (s < REP_CAP) list[s] = make_int2(bh, t);
      }
    }
  }
}

// ---------------------------------------------------------------------------
// Kernel 1b: exact fp64 repair for flagged tokens. Unchanged.
// ---------------------------------------------------------------------------
__global__ __launch_bounds__(256) void repair_kernel(
    const float* __restrict__ qk, const float* __restrict__ rot,
    const int* __restrict__ cnt, const int2* __restrict__ list,
    int* __restrict__ bucket)
{
  const int n = min(*cnt, REP_CAP);
  const int lane = threadIdx.x & 63;
  const int wid  = (blockIdx.x * 256 + threadIdx.x) >> 6;
  const int nw   = gridDim.x * 4;
  for (int idx = wid; idx < n; idx += nw) {
    const int bh = list[idx].x, t = list[idx].y;
    const int b = bh >> 3, hh = bh & 7;
    const float* qrow = qk + ((size_t)b * S_ + t) * D_;
    const float* rcol = rot + hh * 64 + lane;
    double acc = 0.0;
#pragma unroll 8
    for (int f = 0; f < 64; ++f)
      acc = fma((double)qrow[f], (double)rcol[(size_t)f * 512], acc);
    double vM = acc; int iM = lane;
    double vm = acc; int im = lane;
#pragma unroll
    for (int off = 32; off >= 1; off >>= 1) {
      const double voM = __shfl_xor(vM, off); const int ioM = __shfl_xor(iM, off);
      if (voM > vM || (voM == vM && ioM < iM)) { vM = voM; iM = ioM; }
      const double vom = __shfl_xor(vm, off); const int iom = __shfl_xor(im, off);
      if (vom < vm || (vom == vm && iom < im)) { vm = vom; im = iom; }
    }
    if (lane == 0) {
      const int bkt = (vM >= -vm) ? iM : 64 + im;
      bucket[(size_t)bh * S_ + t] = bkt;
    }
  }
}

// ---------------------------------------------------------------------------
// Kernel 2 (REWRITTEN): stable counting sort per (b,h) via ballot-match rank.
// rank(t) = off[bkt] + prefix_over_groups + rank_within_64-token-group.
// Group histogram: hist[g&63][bkt] packs groups g and g+64 in lo/hi u16
// (counts <= 64, no carry). Intra-group rank: 7 ballots (one per bucket bit)
// -> same-bucket lane mask -> popcount of earlier lanes. All writes are
// full-wave (1 coalesced undo + 1 scatter st per group).
// ---------------------------------------------------------------------------
__global__ __launch_bounds__(1024) void sort_kernel(
    const int* __restrict__ bucket, int* __restrict__ st,
    int* __restrict__ undo)
{
  __shared__ uint_ hist[64 * 128];            // 32 KB, [g&63][bkt], lo/hi u16
  __shared__ unsigned short lb[S_];           // 16 KB
  __shared__ int off[128];
  const int tid = threadIdx.x;
  const int bh  = blockIdx.x;
  const size_t base = (size_t)bh * S_;

#pragma unroll
  for (int k = 0; k < 8; ++k) hist[tid + k * 1024] = 0;
  __syncthreads();

  int bkreg[8];
#pragma unroll
  for (int k = 0; k < 8; ++k) {               // coalesced load + packed histogram
    const int t = k * 1024 + tid;
    const int bk = bucket[base + t];
    bkreg[k] = bk;
    lb[t] = (unsigned short)bk;
    const int g = t >> 6;
    atomicAdd(&hist[(g & 63) * 128 + bk], 1u << (16 * (g >> 6)));
  }
  __syncthreads();

  if (tid < 128) {                            // bucket totals (both halves)
    uint_ s = 0;
#pragma unroll
    for (int g = 0; g < 64; ++g) {
      const uint_ wv = hist[g * 128 + tid];
      s += (wv & 0xFFFFu) + (wv >> 16);
    }
    off[tid] = (int)s;
  }
  __syncthreads();
  if (tid == 0) {                             // exclusive prefix over buckets
    int run = 0;
    for (int k = 0; k < 128; ++k) { const int c = off[k]; off[k] = run; run += c; }
  }
  __syncthreads();
  if (tid < 128) {                            // in-place per-bucket group prefix
    uint_ run = (uint_)off[tid];
#pragma unroll
    for (int g = 0; g < 64; ++g) {            // sweep 1: lo halves (groups 0..63)
      const uint_ wv = hist[g * 128 + tid];
      hist[g * 128 + tid] = (wv & 0xFFFF0000u) | run;
      run += (wv & 0xFFFFu);
    }
#pragma unroll
    for (int g = 0; g < 64; ++g) {            // sweep 2: hi halves (groups 64..127)
      const uint_ wv = hist[g * 128 + tid];
      hist[g * 128 + tid] = (wv & 0xFFFFu) | (run << 16);
      run += (wv >> 16);
    }
  }
  __syncthreads();

  const int lane = tid & 63, wv_ = tid >> 6;  // 16 waves x 8 groups each
  const int b = bh >> 3, h = bh & 7;
  const size_t stb = (size_t)b * (H_ * S_) + (size_t)h * S_;
  const unsigned long long ltmask = (1ull << lane) - 1ull;
#pragma unroll
  for (int k = 0; k < 8; ++k) {
    const int g = wv_ * 8 + k;
    const int t = g * 64 + lane;
    const int bk = (int)lb[t];
    unsigned long long same = ~0ull;          // lanes with identical bucket
#pragma unroll
    for (int bit = 0; bit < 7; ++bit) {
      const unsigned long long m = __ballot((bk >> bit) & 1);
      same &= ((bk >> bit) & 1) ? m : ~m;
    }
    const int rloc = __popcll(same & ltmask);
    const uint_ wd = hist[(g & 63) * 128 + bk];
    const int gbase = (int)((wd >> (16 * (g >> 6))) & 0xFFFFu);
    const int rank = gbase + rloc;
    undo[base + t] = h * S_ + rank;           // coalesced over t
    st[stb + rank] = t;                       // full-wave scatter
  }
}

// ---------------------------------------------------------------------------
// Kernel 3: bucketed attention, f16 MFMA, pre-converted f16 gathers, f16 so.
// Unchanged from R5.
// ---------------------------------------------------------------------------
__global__ __launch_bounds__(256, 4) void attn_kernel(
    const _Float16* __restrict__ q16, const _Float16* __restrict__ kn16,
    const _Float16* __restrict__ v16, const int* __restrict__ st,
    _Float16* __restrict__ so, float* __restrict__ slogits)
{
  __shared__ _Float16 sQ[64 * 72];
  __shared__ _Float16 sK[64 * 72];
  __shared__ _Float16 sP[64 * 136];
  __shared__ int sIds[128];

  const int tid = threadIdx.x;
  const int c   = blockIdx.x & (NC_ - 1);
  const int b   = blockIdx.x >> 10;
  const int cm1 = (c + NC_ - 1) & (NC_ - 1);
  const size_t bst = (size_t)b * (H_ * S_);
  const size_t row0 = bst + (size_t)c * 64;
  const size_t row1 = bst + (size_t)cm1 * 64;

  const int lane = tid & 63;
  const int w    = tid >> 6;
  const int m16  = lane & 15;
  const int qd   = lane >> 4;

  if (tid < 128) sIds[tid] = (tid < 64) ? st[row0 + tid] : st[row1 + tid - 64];

  const int r = tid >> 2, qu = tid & 3;
  {
    const int tok = st[row0 + r];
    const size_t go = ((size_t)b * S_ + tok) * 64 + qu * 16;
    const f16x8* sq = (const f16x8*)(q16 + go);
    *(f16x8*)(sQ + r * 72 + qu * 16)     = sq[0];
    *(f16x8*)(sQ + r * 72 + qu * 16 + 8) = sq[1];
    const f16x8* sk = (const f16x8*)(kn16 + go);
    *(f16x8*)(sK + r * 72 + qu * 16)     = sk[0];
    *(f16x8*)(sK + r * 72 + qu * 16 + 8) = sk[1];
  }
  __syncthreads();                            // b0

  f32x4 acc[8];
#pragma unroll
  for (int jt = 0; jt < 8; ++jt) acc[jt] = (f32x4){0.f, 0.f, 0.f, 0.f};

  const _Float16* qrow = sQ + (16 * w + m16) * 72;
  const f16x8 a0 = *(const f16x8*)(qrow + 8 * qd);
  const f16x8 a1 = *(const f16x8*)(qrow + 32 + 8 * qd);

#pragma unroll
  for (int jt = 0; jt < 4; ++jt) {
    const _Float16* krow = sK + (16 * jt + m16) * 72;
    const f16x8 b0 = *(const f16x8*)(krow + 8 * qd);
    const f16x8 b1 = *(const f16x8*)(krow + 32 + 8 * qd);
    acc[jt] = MFMA16(a0, b0, acc[jt]);
    acc[jt] = MFMA16(a1, b1, acc[jt]);
  }
  __syncthreads();                            // b1

  {
    const int tok = st[row1 + r];
    const f16x8* sk = (const f16x8*)(kn16 + ((size_t)b * S_ + tok) * 64 + qu * 16);
    *(f16x8*)(sK + r * 72 + qu * 16)     = sk[0];
    *(f16x8*)(sK + r * 72 + qu * 16 + 8) = sk[1];
  }
  __syncthreads();                            // b2

#pragma unroll
  for (int jt = 4; jt < 8; ++jt) {
    const _Float16* krow = sK + (16 * (jt - 4) + m16) * 72;
    const f16x8 b0 = *(const f16x8*)(krow + 8 * qd);
    const f16x8 b1 = *(const f16x8*)(krow + 32 + 8 * qd);
    acc[jt] = MFMA16(a0, b0, acc[jt]);
    acc[jt] = MFMA16(a1, b1, acc[jt]);
  }

  const int jp = tid >> 2;
  const int tok0 = sIds[2 * jp], tok1 = sIds[2 * jp + 1];
  f16x8 va[2], vb[2];
  {
    const f16x8* s0 = (const f16x8*)(v16 + ((size_t)b * S_ + tok0) * 64 + qu * 16);
    const f16x8* s1 = (const f16x8*)(v16 + ((size_t)b * S_ + tok1) * 64 + qu * 16);
    va[0] = s0[0]; va[1] = s0[1];
    vb[0] = s1[0]; vb[1] = s1[1];
  }

  int rid[4];
#pragma unroll
  for (int rg = 0; rg < 4; ++rg) rid[rg] = sIds[16 * w + 4 * qd + rg];
  float rmax[4] = {-1e30f, -1e30f, -1e30f, -1e30f};
#pragma unroll
  for (int jt = 0; jt < 8; ++jt) {
    const int cid = sIds[16 * jt + m16];
#pragma unroll
    for (int rg = 0; rg < 4; ++rg) {
      float x = acc[jt][rg];
      if (rid[rg] == cid) x = -5e4f;
      acc[jt][rg] = x;
      rmax[rg] = fmaxf(rmax[rg], x);
    }
  }
#pragma unroll
  for (int rg = 0; rg < 4; ++rg) {
    rmax[rg] = fmaxf(rmax[rg], __shfl_xor(rmax[rg], 1));
    rmax[rg] = fmaxf(rmax[rg], __shfl_xor(rmax[rg], 2));
    rmax[rg] = fmaxf(rmax[rg], __shfl_xor(rmax[rg], 4));
    rmax[rg] = fmaxf(rmax[rg], __shfl_xor(rmax[rg], 8));
  }
  float rsum[4] = {0.f, 0.f, 0.f, 0.f};
#pragma unroll
  for (int jt = 0; jt < 8; ++jt)
#pragma unroll
    for (int rg = 0; rg < 4; ++rg) {
      const float e = __expf(acc[jt][rg] - rmax[rg]);
      acc[jt][rg] = e;
      rsum[rg] += e;
    }
#pragma unroll
  for (int rg = 0; rg < 4; ++rg) {
    rsum[rg] += __shfl_xor(rsum[rg], 1);
    rsum[rg] += __shfl_xor(rsum[rg], 2);
    rsum[rg] += __shfl_xor(rsum[rg], 4);
    rsum[rg] += __shfl_xor(rsum[rg], 8);
  }
  float rinv[4];
#pragma unroll
  for (int rg = 0; rg < 4; ++rg) rinv[rg] = 1.f / rsum[rg];
  if (m16 == 0) {
#pragma unroll
    for (int rg = 0; rg < 4; ++rg)
      slogits[row0 + 16 * w + 4 * qd + rg] = rmax[rg] + __logf(rsum[rg]);
  }

#pragma unroll
  for (int jt = 0; jt < 8; ++jt)
#pragma unroll
    for (int rg = 0; rg < 4; ++rg)
      sP[(16 * w + 4 * qd + rg) * 136 + 16 * jt + m16] = (_Float16)acc[jt][rg];

  __syncthreads();                            // b3

  {
    const int j = 2 * jp;
    _Float16* dst = (j < 64) ? (sK + j) : (sQ + (j - 64));
#pragma unroll
    for (int jj = 0; jj < 16; ++jj) {
      const int d = qu * 16 + jj;
      f16x2 pk; pk[0] = va[jj >> 3][jj & 7]; pk[1] = vb[jj >> 3][jj & 7];
      *(f16x2*)(dst + d * 72) = pk;
    }
  }
  __syncthreads();                            // b4

  f32x4 oacc[4];
#pragma unroll
  for (int dt = 0; dt < 4; ++dt) oacc[dt] = (f32x4){0.f, 0.f, 0.f, 0.f};
  const _Float16* prow = sP + (16 * w + m16) * 136;
#pragma unroll
  for (int s = 0; s < 4; ++s) {
    const f16x8 ap = *(const f16x8*)(prow + 32 * s + 8 * qd);
    const _Float16* vbase = (s < 2) ? sK : sQ;
    const int col0 = 32 * (s & 1) + 8 * qd;
#pragma unroll
    for (int dt = 0; dt < 4; ++dt) {
      const f16x8 bv = *(const f16x8*)(vbase + (16 * dt + m16) * 72 + col0);
      oacc[dt] = MFMA16(ap, bv, oacc[dt]);
    }
  }

  const size_t ob = row0 * 64;
#pragma unroll
  for (int dt = 0; dt < 4; ++dt)
#pragma unroll
    for (int rg = 0; rg < 4; ++rg) {
      const int i = 16 * w + 4 * qd + rg;
      const int d = 16 * dt + m16;
      so[ob + (size_t)i * 64 + d] = (_Float16)(oacc[dt][rg] * rinv[rg]);
    }
}

// ---------------------------------------------------------------------------
// Kernel 4: un-sort + combine rounds (f16 so reads). Unchanged.
// ---------------------------------------------------------------------------
__global__ __launch_bounds__(256) void combine_kernel(
    const _Float16* __restrict__ so, const float* __restrict__ slogits,
    const int* __restrict__ undo, float* __restrict__ out)
{
  const int gt = blockIdx.x * 4 + (threadIdx.x >> 6);
  const int d  = threadIdx.x & 63;
  const int b  = gt >> 13;
  const int t  = gt & (S_ - 1);
  const size_t bst = (size_t)b * (H_ * S_);

  int p[8]; float l[8];
#pragma unroll
  for (int h = 0; h < 8; ++h) {
    p[h] = undo[((size_t)b * 8 + h) * S_ + t];
    l[h] = slogits[bst + p[h]];
  }
  float m = l[0];
#pragma unroll
  for (int h = 1; h < 8; ++h) m = fmaxf(m, l[h]);
  float wv[8], W = 0.f;
#pragma unroll
  for (int h = 0; h < 8; ++h) { wv[h] = expf(l[h] - m); W += wv[h]; }
  const float iW = 1.f / W;
  float acc = 0.f;
#pragma unroll
  for (int h = 0; h < 8; ++h)
    acc = fmaf(wv[h], (float)so[(bst + (size_t)p[h]) * 64 + d], acc);
  out[(size_t)gt * 64 + d] = acc * iW;
}

// ---------------------------------------------------------------------------
extern "C" void kernel_launch(void* const* d_in, const int* in_sizes, int n_in,
                              void* d_out, int out_size, void* d_ws, size_t ws_size,
                              hipStream_t stream)
{
  const float* qk  = (const float*)d_in[0];
  const float* v   = (const float*)d_in[1];
  const float* rot = (const float*)d_in[2];
  float* out = (float*)d_out;

  char* ws = (char*)d_ws;
  const size_t MB = 1ull << 20, KB = 1024;
  int*      bucket = (int*)      (ws + 0 * MB);
  int*      st     = (int*)      (ws + 2 * MB);
  int*      undo   = (int*)      (ws + 4 * MB);
  float*    slog   = (float*)    (ws + 6 * MB);
  _Float16* q16    = (_Float16*) (ws + 8 * MB);
  _Float16* kn16   = (_Float16*) (ws + 16 * MB);
  _Float16* v16    = (_Float16*) (ws + 24 * MB);
  _Float16* qlo    = (_Float16*) (ws + 32 * MB);
  _Float16* rotHi  = (_Float16*) (ws + 40 * MB);
  _Float16* rotLo  = (_Float16*) (ws + 40 * MB + 64 * KB);
  int*      cnt    = (int*)      (ws + 40 * MB + 128 * KB);
  int2*     list   = (int2*)     (ws + 40 * MB + 192 * KB);
  _Float16* so     = (_Float16*) (ws + 41 * MB);
  if (ws_size < 106 * MB) return;

  hipLaunchKernelGGL(prep_rot_kernel, dim3(8),           dim3(256),  0, stream, rot, rotHi, rotLo, cnt);
  hipLaunchKernelGGL(prep_tok_kernel, dim3(1024),        dim3(256),  0, stream, qk, v, q16, qlo, kn16, v16);
  hipLaunchKernelGGL(hash_kernel,     dim3(64 * 64),     dim3(256),  0, stream, q16, qlo, rotHi, rotLo, bucket, cnt, list);
  hipLaunchKernelGGL(repair_kernel,   dim3(128),         dim3(256),  0, stream, qk, rot, cnt, list, bucket);
  hipLaunchKernelGGL(sort_kernel,     dim3(64),          dim3(1024), 0, stream, bucket, st, undo);
  hipLaunchKernelGGL(attn_kernel,     dim3(B_ * NC_),    dim3(256),  0, stream, q16, kn16, v16, st, so, slog);
  hipLaunchKernelGGL(combine_kernel,  dim3(B_ * S_ / 4), dim3(256),  0, stream, so, slog, undo, out);
}

// Round 7
// 209.219 us; speedup vs baseline: 1.4101x; 1.1260x over previous
//
#include <hip/hip_runtime.h>
#include <math.h>

#define B_  8
#define S_  8192
#define D_  64
#define H_  8
#define NB_ 128
#define NC_ 1024
#define REP_CAP 65536
#define T2_ 2e-3f   // repair margin >= 10x the split-f16 worst-case error (~1.5e-4)

typedef _Float16 f16x8 __attribute__((ext_vector_type(8)));
typedef _Float16 f16x2 __attribute__((ext_vector_type(2)));
typedef float    f32x4 __attribute__((ext_vector_type(4)));
typedef unsigned int uint_;

#define MFMA16(A, Bv, C) __builtin_amdgcn_mfma_f32_16x16x32_f16(A, Bv, C, 0, 0, 0)

// ---------------------------------------------------------------------------
// Kernel 0a: rot prep — transpose+split rot into [h][i][f] f16 hi/lo; zero cnt.
// ---------------------------------------------------------------------------
__global__ __launch_bounds__(256) void prep_rot_kernel(
    const float* __restrict__ rot, _Float16* __restrict__ rotHi,
    _Float16* __restrict__ rotLo, int* __restrict__ cnt)
{
  __shared__ float rs[64 * 64];               // [f][i]
  const int tid = threadIdx.x, h = blockIdx.x;
  if (h == 0 && tid == 0) *cnt = 0;
#pragma unroll
  for (int it = 0; it < 16; ++it) {
    const int f = it * 4 + (tid >> 6), i = tid & 63;
    rs[f * 64 + i] = rot[f * 512 + h * 64 + i];
  }
  __syncthreads();
  const int i = tid & 63, grp = tid >> 6;
  _Float16 hi[16], lo[16];
#pragma unroll
  for (int ff = 0; ff < 16; ++ff) {
    const float x = rs[(grp * 16 + ff) * 64 + i];
    hi[ff] = (_Float16)x;
    lo[ff] = (_Float16)(x - (float)hi[ff]);
  }
  f16x8* dH = (f16x8*)(rotHi + h * 4096 + i * 64 + grp * 16);
  f16x8* dL = (f16x8*)(rotLo + h * 4096 + i * 64 + grp * 16);
  dH[0] = ((f16x8*)hi)[0]; dH[1] = ((f16x8*)hi)[1];
  dL[0] = ((f16x8*)lo)[0]; dL[1] = ((f16x8*)lo)[1];
}

// ---------------------------------------------------------------------------
// Kernel 0b: token prep — q16 (f16), kn16 (pre-normalized keys), v16.
// ---------------------------------------------------------------------------
__global__ __launch_bounds__(256) void prep_tok_kernel(
    const float* __restrict__ qk, const float* __restrict__ v,
    _Float16* __restrict__ q16, _Float16* __restrict__ kn16,
    _Float16* __restrict__ v16)
{
  const int gt = blockIdx.x * 64 + (threadIdx.x >> 2);
  const int qu = threadIdx.x & 3;
  const size_t off = (size_t)gt * 64 + qu * 16;
  float x[16];
#pragma unroll
  for (int k = 0; k < 4; ++k) ((float4*)x)[k] = ((const float4*)(qk + off))[k];
  float ss = 0.f;
#pragma unroll
  for (int k = 0; k < 16; ++k) ss = fmaf(x[k], x[k], ss);
  ss += __shfl_xor(ss, 1); ss += __shfl_xor(ss, 2);
  const float inv = 0.125f / (sqrtf(ss) + 1e-6f);
  f16x8 qh[2], kn[2];
#pragma unroll
  for (int j = 0; j < 16; ++j) {
    qh[j >> 3][j & 7] = (_Float16)x[j];
    kn[j >> 3][j & 7] = (_Float16)(x[j] * inv);
  }
  ((f16x8*)(q16  + off))[0] = qh[0]; ((f16x8*)(q16  + off))[1] = qh[1];
  ((f16x8*)(kn16 + off))[0] = kn[0]; ((f16x8*)(kn16 + off))[1] = kn[1];
  float y[16];
#pragma unroll
  for (int k = 0; k < 4; ++k) ((float4*)y)[k] = ((const float4*)(v + off))[k];
  f16x8 vv[2];
#pragma unroll
  for (int j = 0; j < 16; ++j) vv[j >> 3][j & 7] = (_Float16)y[j];
  ((f16x8*)(v16 + off))[0] = vv[0]; ((f16x8*)(v16 + off))[1] = vv[1];
}

// ---------------------------------------------------------------------------
// Kernel 1 (RESTRUCTURED): hash, all 8 h per block (64-token tile).
// B-frags split from fp32 qk ONCE in registers (bit-identical to prep path);
// per-h rot slice staged in LDS (L2-hot, 16 KB), A-frags via ds_read_b128.
// Reduction: keyed low-6-mantissa-bit index + v_med3 top-2, 2 shuffle merges.
// Tokens with any margin < T2 -> exact-fp64 repair (buckets fp64-exact).
// ---------------------------------------------------------------------------
__global__ __launch_bounds__(256) void hash_kernel(
    const float* __restrict__ qk,
    const _Float16* __restrict__ rotHi, const _Float16* __restrict__ rotLo,
    int* __restrict__ bucket, int* __restrict__ cnt, int2* __restrict__ list)
{
  __shared__ _Float16 rH[64 * 72];            // 9216 B
  __shared__ _Float16 rL[64 * 72];            // 9216 B
  const int tid  = threadIdx.x;
  const int tile = blockIdx.x & 127;          // 128 tiles x 64 tokens
  const int b    = blockIdx.x >> 7;
  const int lane = tid & 63, w = tid >> 6;
  const int m16  = lane & 15, qd = lane >> 4;

  const int t = tile * 64 + w * 16 + m16;
  f16x8 BH0, BH1, BL0, BL1;                   // split-f16 B-fragments
  {
    const float* src = qk + ((size_t)b * S_ + t) * 64 + 8 * qd;
    float x[16];
    ((float4*)x)[0] = ((const float4*)src)[0];
    ((float4*)x)[1] = ((const float4*)(src + 4))[0];
    ((float4*)x)[2] = ((const float4*)(src + 32))[0];
    ((float4*)x)[3] = ((const float4*)(src + 36))[0];
#pragma unroll
    for (int j = 0; j < 8; ++j) {
      const _Float16 h0 = (_Float16)x[j];
      BH0[j] = h0; BL0[j] = (_Float16)(x[j] - (float)h0);
      const _Float16 h1 = (_Float16)x[j + 8];
      BH1[j] = h1; BL1[j] = (_Float16)(x[j + 8] - (float)h1);
    }
  }
  const int srow = tid >> 2, scol = (tid & 3) * 16;
  const uint_ qd16 = (uint_)(qd << 4);

#pragma unroll 1
  for (int h = 0; h < 8; ++h) {
    __syncthreads();                          // LDS reuse guard
    {                                         // stage rot h-slice
      const _Float16* sH = rotHi + h * 4096 + srow * 64 + scol;
      const _Float16* sL = rotLo + h * 4096 + srow * 64 + scol;
      *(f16x8*)(rH + srow * 72 + scol)     = ((const f16x8*)sH)[0];
      *(f16x8*)(rH + srow * 72 + scol + 8) = ((const f16x8*)sH)[1];
      *(f16x8*)(rL + srow * 72 + scol)     = ((const f16x8*)sL)[0];
      *(f16x8*)(rL + srow * 72 + scol + 8) = ((const f16x8*)sL)[1];
    }
    __syncthreads();

    f32x4 acc[4];
#pragma unroll
    for (int mt = 0; mt < 4; ++mt) acc[mt] = (f32x4){0.f, 0.f, 0.f, 0.f};
#pragma unroll
    for (int mt = 0; mt < 4; ++mt) {
      const _Float16* aH = rH + (16 * mt + m16) * 72 + 8 * qd;
      const _Float16* aL = rL + (16 * mt + m16) * 72 + 8 * qd;
      const f16x8 AH0 = *(const f16x8*)aH;
      const f16x8 AH1 = *(const f16x8*)(aH + 32);
      const f16x8 AL0 = *(const f16x8*)aL;
      const f16x8 AL1 = *(const f16x8*)(aL + 32);
      acc[mt] = MFMA16(AH0, BH0, acc[mt]);
      acc[mt] = MFMA16(AH1, BH1, acc[mt]);
      acc[mt] = MFMA16(AH0, BL0, acc[mt]);
      acc[mt] = MFMA16(AH1, BL1, acc[mt]);
      acc[mt] = MFMA16(AL0, BH0, acc[mt]);
      acc[mt] = MFMA16(AL1, BH1, acc[mt]);
    }

    float v1M = -1e30f, v2M = -1e30f, v1m = 1e30f, v2m = 1e30f;
#pragma unroll
    for (int mt = 0; mt < 4; ++mt)
#pragma unroll
      for (int rg = 0; rg < 4; ++rg) {
        uint_ u = __float_as_uint(acc[mt][rg]);
        u = (u & 0xFFFFFFC0u) | qd16 | (uint_)((mt << 2) | rg);
        const float xk = __uint_as_float(u);
        v2M = __builtin_amdgcn_fmed3f(v1M, v2M, xk);
        v1M = fmaxf(v1M, xk);
        v2m = __builtin_amdgcn_fmed3f(v1m, v2m, xk);
        v1m = fminf(v1m, xk);
      }
#pragma unroll
    for (int off = 16; off <= 32; off <<= 1) {
      const float o1M = __shfl_xor(v1M, off), o2M = __shfl_xor(v2M, off);
      v2M = __builtin_amdgcn_fmed3f(v1M, o1M, fmaxf(v2M, o2M));
      v1M = fmaxf(v1M, o1M);
      const float o1m = __shfl_xor(v1m, off), o2m = __shfl_xor(v2m, off);
      v2m = __builtin_amdgcn_fmed3f(v1m, o1m, fminf(v2m, o2m));
      v1m = fminf(v1m, o1m);
    }
    if (qd == 0) {
      const uint_ cM = __float_as_uint(v1M) & 63u;
      const uint_ cm = __float_as_uint(v1m) & 63u;
      const int ixM = 16 * (int)((cM >> 2) & 3u) + 4 * (int)(cM >> 4) + (int)(cM & 3u);
      const int ixm = 16 * (int)((cm >> 2) & 3u) + 4 * (int)(cm >> 4) + (int)(cm & 3u);
      const int bkt = (v1M >= -v1m) ? ixM : 64 + ixm;
      bucket[((size_t)(b * 8 + h)) * S_ + t] = bkt;
      const bool flag = ((v1M - v2M) < T2_) | ((v2m - v1m) < T2_) |
                        (fabsf(v1M + v1m) < T2_);
      if (flag) {
        const int s = atomicAdd(cnt, 1);
        if (s < REP_CAP) list[s] = make_int2(b * 8 + h, t);
      }
    }
  }
}

// ---------------------------------------------------------------------------
// Kernel 1b: exact fp64 repair for flagged tokens. Unchanged.
// ---------------------------------------------------------------------------
__global__ __launch_bounds__(256) void repair_kernel(
    const float* __restrict__ qk, const float* __restrict__ rot,
    const int* __restrict__ cnt, const int2* __restrict__ list,
    int* __restrict__ bucket)
{
  const int n = min(*cnt, REP_CAP);
  const int lane = threadIdx.x & 63;
  const int wid  = (blockIdx.x * 256 + threadIdx.x) >> 6;
  const int nw   = gridDim.x * 4;
  for (int idx = wid; idx < n; idx += nw) {
    const int bh = list[idx].x, t = list[idx].y;
    const int b = bh >> 3, hh = bh & 7;
    const float* qrow = qk + ((size_t)b * S_ + t) * D_;
    const float* rcol = rot + hh * 64 + lane;
    double acc = 0.0;
#pragma unroll 8
    for (int f = 0; f < 64; ++f)
      acc = fma((double)qrow[f], (double)rcol[(size_t)f * 512], acc);
    double vM = acc; int iM = lane;
    double vm = acc; int im = lane;
#pragma unroll
    for (int off = 32; off >= 1; off >>= 1) {
      const double voM = __shfl_xor(vM, off); const int ioM = __shfl_xor(iM, off);
      if (voM > vM || (voM == vM && ioM < iM)) { vM = voM; iM = ioM; }
      const double vom = __shfl_xor(vm, off); const int iom = __shfl_xor(im, off);
      if (vom < vm || (vom == vm && iom < im)) { vm = vom; im = iom; }
    }
    if (lane == 0) {
      const int bkt = (vM >= -vm) ? iM : 64 + im;
      bucket[(size_t)bh * S_ + t] = bkt;
    }
  }
}

// ---------------------------------------------------------------------------
// Kernel 2: ballot-match stable counting sort. undo output dropped (combine
// no longer needs it — attn scatters results to original token order).
// ---------------------------------------------------------------------------
__global__ __launch_bounds__(1024) void sort_kernel(
    const int* __restrict__ bucket, int* __restrict__ st)
{
  __shared__ uint_ hist[64 * 128];            // [g&63][bkt], lo/hi u16
  __shared__ unsigned short lb[S_];
  __shared__ int off[128];
  const int tid = threadIdx.x;
  const int bh  = blockIdx.x;
  const size_t base = (size_t)bh * S_;

#pragma unroll
  for (int k = 0; k < 8; ++k) hist[tid + k * 1024] = 0;
  __syncthreads();

#pragma unroll
  for (int k = 0; k < 8; ++k) {
    const int t = k * 1024 + tid;
    const int bk = bucket[base + t];
    lb[t] = (unsigned short)bk;
    const int g = t >> 6;
    atomicAdd(&hist[(g & 63) * 128 + bk], 1u << (16 * (g >> 6)));
  }
  __syncthreads();

  if (tid < 128) {
    uint_ s = 0;
#pragma unroll
    for (int g = 0; g < 64; ++g) {
      const uint_ wv = hist[g * 128 + tid];
      s += (wv & 0xFFFFu) + (wv >> 16);
    }
    off[tid] = (int)s;
  }
  __syncthreads();
  if (tid == 0) {
    int run = 0;
    for (int k = 0; k < 128; ++k) { const int c = off[k]; off[k] = run; run += c; }
  }
  __syncthreads();
  if (tid < 128) {
    uint_ run = (uint_)off[tid];
#pragma unroll
    for (int g = 0; g < 64; ++g) {
      const uint_ wv = hist[g * 128 + tid];
      hist[g * 128 + tid] = (wv & 0xFFFF0000u) | run;
      run += (wv & 0xFFFFu);
    }
#pragma unroll
    for (int g = 0; g < 64; ++g) {
      const uint_ wv = hist[g * 128 + tid];
      hist[g * 128 + tid] = (wv & 0xFFFFu) | (run << 16);
      run += (wv >> 16);
    }
  }
  __syncthreads();

  const int lane = tid & 63, wv_ = tid >> 6;
  const int b = bh >> 3, h = bh & 7;
  const size_t stb = (size_t)b * (H_ * S_) + (size_t)h * S_;
  const unsigned long long ltmask = (1ull << lane) - 1ull;
#pragma unroll
  for (int k = 0; k < 8; ++k) {
    const int g = wv_ * 8 + k;
    const int t = g * 64 + lane;
    const int bk = (int)lb[t];
    unsigned long long same = ~0ull;
#pragma unroll
    for (int bit = 0; bit < 7; ++bit) {
      const unsigned long long m = __ballot((bk >> bit) & 1);
      same &= ((bk >> bit) & 1) ? m : ~m;
    }
    const int rloc = __popcll(same & ltmask);
    const uint_ wd = hist[(g & 63) * 128 + bk];
    const int gbase = (int)((wd >> (16 * (g >> 6))) & 0xFFFFu);
    st[stb + gbase + rloc] = t;
  }
}

// ---------------------------------------------------------------------------
// Kernel 3: bucketed attention, f16 MFMA. Epilogue now SCATTERS so/slog to
// original token order (so[b][h][tok]) so combine can stream.
// ---------------------------------------------------------------------------
__global__ __launch_bounds__(256, 4) void attn_kernel(
    const _Float16* __restrict__ q16, const _Float16* __restrict__ kn16,
    const _Float16* __restrict__ v16, const int* __restrict__ st,
    _Float16* __restrict__ so, float* __restrict__ slog)
{
  __shared__ _Float16 sQ[64 * 72];
  __shared__ _Float16 sK[64 * 72];
  __shared__ _Float16 sP[64 * 136];
  __shared__ int sIds[128];

  const int tid = threadIdx.x;
  const int c   = blockIdx.x & (NC_ - 1);
  const int b   = blockIdx.x >> 10;
  const int cm1 = (c + NC_ - 1) & (NC_ - 1);
  const size_t bst = (size_t)b * (H_ * S_);
  const size_t row0 = bst + (size_t)c * 64;
  const size_t row1 = bst + (size_t)cm1 * 64;

  const int lane = tid & 63;
  const int w    = tid >> 6;
  const int m16  = lane & 15;
  const int qd   = lane >> 4;

  if (tid < 128) sIds[tid] = (tid < 64) ? st[row0 + tid] : st[row1 + tid - 64];

  const int r = tid >> 2, qu = tid & 3;
  {
    const int tok = st[row0 + r];
    const size_t go = ((size_t)b * S_ + tok) * 64 + qu * 16;
    const f16x8* sq = (const f16x8*)(q16 + go);
    *(f16x8*)(sQ + r * 72 + qu * 16)     = sq[0];
    *(f16x8*)(sQ + r * 72 + qu * 16 + 8) = sq[1];
    const f16x8* sk = (const f16x8*)(kn16 + go);
    *(f16x8*)(sK + r * 72 + qu * 16)     = sk[0];
    *(f16x8*)(sK + r * 72 + qu * 16 + 8) = sk[1];
  }
  __syncthreads();                            // b0

  f32x4 acc[8];
#pragma unroll
  for (int jt = 0; jt < 8; ++jt) acc[jt] = (f32x4){0.f, 0.f, 0.f, 0.f};

  const _Float16* qrow = sQ + (16 * w + m16) * 72;
  const f16x8 a0 = *(const f16x8*)(qrow + 8 * qd);
  const f16x8 a1 = *(const f16x8*)(qrow + 32 + 8 * qd);

#pragma unroll
  for (int jt = 0; jt < 4; ++jt) {
    const _Float16* krow = sK + (16 * jt + m16) * 72;
    const f16x8 b0 = *(const f16x8*)(krow + 8 * qd);
    const f16x8 b1 = *(const f16x8*)(krow + 32 + 8 * qd);
    acc[jt] = MFMA16(a0, b0, acc[jt]);
    acc[jt] = MFMA16(a1, b1, acc[jt]);
  }
  __syncthreads();                            // b1

  {
    const int tok = st[row1 + r];
    const f16x8* sk = (const f16x8*)(kn16 + ((size_t)b * S_ + tok) * 64 + qu * 16);
    *(f16x8*)(sK + r * 72 + qu * 16)     = sk[0];
    *(f16x8*)(sK + r * 72 + qu * 16 + 8) = sk[1];
  }
  __syncthreads();                            // b2

#pragma unroll
  for (int jt = 4; jt < 8; ++jt) {
    const _Float16* krow = sK + (16 * (jt - 4) + m16) * 72;
    const f16x8 b0 = *(const f16x8*)(krow + 8 * qd);
    const f16x8 b1 = *(const f16x8*)(krow + 32 + 8 * qd);
    acc[jt] = MFMA16(a0, b0, acc[jt]);
    acc[jt] = MFMA16(a1, b1, acc[jt]);
  }

  const int jp = tid >> 2;
  const int tok0 = sIds[2 * jp], tok1 = sIds[2 * jp + 1];
  f16x8 va[2], vb[2];
  {
    const f16x8* s0 = (const f16x8*)(v16 + ((size_t)b * S_ + tok0) * 64 + qu * 16);
    const f16x8* s1 = (const f16x8*)(v16 + ((size_t)b * S_ + tok1) * 64 + qu * 16);
    va[0] = s0[0]; va[1] = s0[1];
    vb[0] = s1[0]; vb[1] = s1[1];
  }

  int rid[4];
#pragma unroll
  for (int rg = 0; rg < 4; ++rg) rid[rg] = sIds[16 * w + 4 * qd + rg];
  float rmax[4] = {-1e30f, -1e30f, -1e30f, -1e30f};
#pragma unroll
  for (int jt = 0; jt < 8; ++jt) {
    const int cid = sIds[16 * jt + m16];
#pragma unroll
    for (int rg = 0; rg < 4; ++rg) {
      float x = acc[jt][rg];
      if (rid[rg] == cid) x = -5e4f;
      acc[jt][rg] = x;
      rmax[rg] = fmaxf(rmax[rg], x);
    }
  }
#pragma unroll
  for (int rg = 0; rg < 4; ++rg) {
    rmax[rg] = fmaxf(rmax[rg], __shfl_xor(rmax[rg], 1));
    rmax[rg] = fmaxf(rmax[rg], __shfl_xor(rmax[rg], 2));
    rmax[rg] = fmaxf(rmax[rg], __shfl_xor(rmax[rg], 4));
    rmax[rg] = fmaxf(rmax[rg], __shfl_xor(rmax[rg], 8));
  }
  float rsum[4] = {0.f, 0.f, 0.f, 0.f};
#pragma unroll
  for (int jt = 0; jt < 8; ++jt)
#pragma unroll
    for (int rg = 0; rg < 4; ++rg) {
      const float e = __expf(acc[jt][rg] - rmax[rg]);
      acc[jt][rg] = e;
      rsum[rg] += e;
    }
#pragma unroll
  for (int rg = 0; rg < 4; ++rg) {
    rsum[rg] += __shfl_xor(rsum[rg], 1);
    rsum[rg] += __shfl_xor(rsum[rg], 2);
    rsum[rg] += __shfl_xor(rsum[rg], 4);
    rsum[rg] += __shfl_xor(rsum[rg], 8);
  }
  float rinv[4];
#pragma unroll
  for (int rg = 0; rg < 4; ++rg) rinv[rg] = 1.f / rsum[rg];

  const int hh = c >> 7;                      // hash round of this chunk
  const size_t hb = ((size_t)(b * 8 + hh)) * S_;
  if (m16 == 0) {
#pragma unroll
    for (int rg = 0; rg < 4; ++rg)
      slog[hb + rid[rg]] = rmax[rg] + __logf(rsum[rg]);
  }

#pragma unroll
  for (int jt = 0; jt < 8; ++jt)
#pragma unroll
    for (int rg = 0; rg < 4; ++rg)
      sP[(16 * w + 4 * qd + rg) * 136 + 16 * jt + m16] = (_Float16)acc[jt][rg];

  __syncthreads();                            // b3

  {
    const int j = 2 * jp;
    _Float16* dst = (j < 64) ? (sK + j) : (sQ + (j - 64));
#pragma unroll
    for (int jj = 0; jj < 16; ++jj) {
      const int d = qu * 16 + jj;
      f16x2 pk; pk[0] = va[jj >> 3][jj & 7]; pk[1] = vb[jj >> 3][jj & 7];
      *(f16x2*)(dst + d * 72) = pk;
    }
  }
  __syncthreads();                            // b4

  f32x4 oacc[4];
#pragma unroll
  for (int dt = 0; dt < 4; ++dt) oacc[dt] = (f32x4){0.f, 0.f, 0.f, 0.f};
  const _Float16* prow = sP + (16 * w + m16) * 136;
#pragma unroll
  for (int s = 0; s < 4; ++s) {
    const f16x8 ap = *(const f16x8*)(prow + 32 * s + 8 * qd);
    const _Float16* vbase = (s < 2) ? sK : sQ;
    const int col0 = 32 * (s & 1) + 8 * qd;
#pragma unroll
    for (int dt = 0; dt < 4; ++dt) {
      const f16x8 bv = *(const f16x8*)(vbase + (16 * dt + m16) * 72 + col0);
      oacc[dt] = MFMA16(ap, bv, oacc[dt]);
    }
  }

  // scatter output rows to original token positions
#pragma unroll
  for (int dt = 0; dt < 4; ++dt)
#pragma unroll
    for (int rg = 0; rg < 4; ++rg)
      so[(hb + rid[rg]) * 64 + 16 * dt + m16] = (_Float16)(oacc[dt][rg] * rinv[rg]);
}

// ---------------------------------------------------------------------------
// Kernel 4: combine rounds — fully streaming (so/slog already in token order).
// ---------------------------------------------------------------------------
__global__ __launch_bounds__(256) void combine_kernel(
    const _Float16* __restrict__ so, const float* __restrict__ slog,
    float* __restrict__ out)
{
  const int gt = blockIdx.x * 4 + (threadIdx.x >> 6);
  const int d  = threadIdx.x & 63;
  const int b  = gt >> 13;
  const int t  = gt & (S_ - 1);

  float l[8];
#pragma unroll
  for (int h = 0; h < 8; ++h)
    l[h] = slog[((size_t)(b * 8 + h)) * S_ + t];
  float m = l[0];
#pragma unroll
  for (int h = 1; h < 8; ++h) m = fmaxf(m, l[h]);
  float wv[8], W = 0.f;
#pragma unroll
  for (int h = 0; h < 8; ++h) { wv[h] = expf(l[h] - m); W += wv[h]; }
  const float iW = 1.f / W;
  float acc = 0.f;
#pragma unroll
  for (int h = 0; h < 8; ++h)
    acc = fmaf(wv[h], (float)so[(((size_t)(b * 8 + h)) * S_ + t) * 64 + d], acc);
  out[(size_t)gt * 64 + d] = acc * iW;
}

// ---------------------------------------------------------------------------
extern "C" void kernel_launch(void* const* d_in, const int* in_sizes, int n_in,
                              void* d_out, int out_size, void* d_ws, size_t ws_size,
                              hipStream_t stream)
{
  const float* qk  = (const float*)d_in[0];
  const float* v   = (const float*)d_in[1];
  const float* rot = (const float*)d_in[2];
  float* out = (float*)d_out;

  char* ws = (char*)d_ws;
  const size_t MB = 1ull << 20, KB = 1024;
  int*      bucket = (int*)      (ws + 0 * MB);   // 2 MB
  int*      st     = (int*)      (ws + 2 * MB);   // 2 MB
  float*    slog   = (float*)    (ws + 4 * MB);   // 2 MB
  _Float16* q16    = (_Float16*) (ws + 8 * MB);   // 8 MB
  _Float16* kn16   = (_Float16*) (ws + 16 * MB);  // 8 MB
  _Float16* v16    = (_Float16*) (ws + 24 * MB);  // 8 MB
  _Float16* rotHi  = (_Float16*) (ws + 32 * MB);            // 64 KB
  _Float16* rotLo  = (_Float16*) (ws + 32 * MB + 64 * KB);  // 64 KB
  int*      cnt    = (int*)      (ws + 32 * MB + 128 * KB);
  int2*     list   = (int2*)     (ws + 32 * MB + 192 * KB); // 512 KB
  _Float16* so     = (_Float16*) (ws + 33 * MB);  // 64 MB -> ends at 97 MB
  if (ws_size < 98 * MB) return;

  hipLaunchKernelGGL(prep_rot_kernel, dim3(8),           dim3(256),  0, stream, rot, rotHi, rotLo, cnt);
  hipLaunchKernelGGL(prep_tok_kernel, dim3(1024),        dim3(256),  0, stream, qk, v, q16, kn16, v16);
  hipLaunchKernelGGL(hash_kernel,     dim3(8 * 128),     dim3(256),  0, stream, qk, rotHi, rotLo, bucket, cnt, list);
  hipLaunchKernelGGL(repair_kernel,   dim3(128),         dim3(256),  0, stream, qk, rot, cnt, list, bucket);
  hipLaunchKernelGGL(sort_kernel,     dim3(64),          dim3(1024), 0, stream, bucket, st);
  hipLaunchKernelGGL(attn_kernel,     dim3(B_ * NC_),    dim3(256),  0, stream, q16, kn16, v16, st, so, slog);
  hipLaunchKernelGGL(combine_kernel,  dim3(B_ * S_ / 4), dim3(256),  0, stream, so, slog, out);
}